// Round 1
// 403.763 us; speedup vs baseline: 1.2563x; 1.2563x over previous
//
#include <hip/hip_runtime.h>
#include <cstdint>
#include <cstddef>

typedef __bf16 bf16;
typedef __bf16 bf16x8 __attribute__((ext_vector_type(8)));
typedef float floatx4 __attribute__((ext_vector_type(4)));
typedef float floatx8 __attribute__((ext_vector_type(8)));
typedef unsigned int u32;

constexpr int Bb = 4, Ll = 4096, Dd = 1024;
constexpr int M  = Bb * Ll;          // 16384 rows
constexpr int NC = 64, CT = 64;      // chunks per sequence, chunk length

// async 16B global->LDS (width=16 emits global_load_lds_dwordx4)
typedef const __attribute__((address_space(1))) u32 glb_u32;
typedef __attribute__((address_space(3))) u32 lds_u32;
__device__ __forceinline__ void gld16(const bf16* g, bf16* l) {
  __builtin_amdgcn_global_load_lds((glb_u32*)g, (lds_u32*)l, 16, 0, 0);
}

// ---------------- W f32 -> bf16 one-shot convert (1024x1024) ----------------
__global__ __launch_bounds__(256) void convw(
    const float* __restrict__ W, bf16* __restrict__ Wb)
{
  size_t base = ((size_t)blockIdx.x * 256 + threadIdx.x) * 8;
  floatx8 w = *(const floatx8*)(W + base);
  bf16x8 o;
  #pragma unroll
  for (int j = 0; j < 8; ++j) o[j] = (bf16)w[j];
  *(bf16x8*)(Wb + base) = o;
}

// ---------------- prep: token-shift mix, f32 x -> bf16 mixed arrays ----------------
__global__ __launch_bounds__(256) void prep2(
    const float* __restrict__ x, const float* __restrict__ ma, const float* __restrict__ mb,
    bf16* __restrict__ oa, bf16* __restrict__ ob)
{
  size_t base = ((size_t)blockIdx.x * 256 + threadIdx.x) * 8;
  int d = (int)(base & (size_t)(Dd - 1));
  int l = (int)((base / Dd) & (size_t)(Ll - 1));
  floatx8 xc = *(const floatx8*)(x + base);
  floatx8 xp = l ? *(const floatx8*)(x + base - Dd) : (floatx8)(0.0f);
  floatx8 a = *(const floatx8*)(ma + d);
  floatx8 b = *(const floatx8*)(mb + d);
  bf16x8 ra, rb;
  #pragma unroll
  for (int j = 0; j < 8; ++j) {
    ra[j] = (bf16)(xc[j] * a[j] + xp[j] * (1.0f - a[j]));
    rb[j] = (bf16)(xc[j] * b[j] + xp[j] * (1.0f - b[j]));
  }
  *(bf16x8*)(oa + base) = ra;
  *(bf16x8*)(ob + base) = rb;
}

__global__ __launch_bounds__(256) void prep1(
    const float* __restrict__ x, const float* __restrict__ ma, bf16* __restrict__ oa)
{
  size_t base = ((size_t)blockIdx.x * 256 + threadIdx.x) * 8;
  int d = (int)(base & (size_t)(Dd - 1));
  int l = (int)((base / Dd) & (size_t)(Ll - 1));
  floatx8 xc = *(const floatx8*)(x + base);
  floatx8 xp = l ? *(const floatx8*)(x + base - Dd) : (floatx8)(0.0f);
  floatx8 a = *(const floatx8*)(ma + d);
  bf16x8 ra;
  #pragma unroll
  for (int j = 0; j < 8; ++j)
    ra[j] = (bf16)(xc[j] * a[j] + xp[j] * (1.0f - a[j]));
  *(bf16x8*)(oa + base) = ra;
}

// ---------------- GEMM: C[m,n] = sum_k A[m,k]*W[n,k]; A,W bf16, both async DMA ----
// Both LDS tiles use an XOR column-unit swizzle (rule #21: linear LDS dest,
// inverse-swizzled GLOBAL source, same swizzle on the ds_read). Unit permutation
// cu ^= (row>>1)&3 lands each 16-lane fragment read on every bank exactly 2x
// (2-way aliasing is free per m136) vs the 8-way conflict of the linear layout.
// ACT: 0 = f32 out, 1 = sigmoid bf16 out, 2 = bf16 out
template <int ACT>
__global__ __launch_bounds__(256) void gemm_bb(
    const bf16* __restrict__ A, const bf16* __restrict__ W, void* __restrict__ Cout)
{
  __shared__ __align__(16) bf16 As[128 * 32];
  __shared__ __align__(16) bf16 Bs[128 * 32];
  const int tid  = threadIdx.x;
  const int lane = tid & 63;
  const int w    = tid >> 6;
  const int wm   = (w >> 1) * 64, wn = (w & 1) * 64;
  const int fr   = lane & 15;
  const int cu   = lane >> 4;                      // which 16B column-unit this lane reads
  // swizzled read offset: for row = 16a + fr, (row>>1)&3 == (fr>>1)&3 (a*16>>1 is mult of 8)
  const int soff = ((cu ^ ((fr >> 1) & 3)) << 3);  // elems

  // XCD-bijective remap: 1024 blocks, 8 XCDs, chunk=128 -> each A row-panel's
  // 8 n-blocks land on ONE XCD's L2 (kills the 8x panel re-fetch).
  const int flat = (int)(blockIdx.y * 8 + blockIdx.x);
  const int nid  = (flat & 7) * 128 + (flat >> 3);
  const int m0   = (nid >> 3) * 128, n0 = (nid & 7) * 128;

  const int u0 = tid, u1 = tid + 256;              // 16B staging units
  const int r0 = u0 >> 2, c0 = (((u0 & 3) ^ ((r0 >> 1) & 3)) << 3);
  const int r1 = u1 >> 2, c1 = (((u1 & 3) ^ ((r1 >> 1) & 3)) << 3);

  floatx4 acc[4][4];
  #pragma unroll
  for (int i = 0; i < 4; ++i)
    #pragma unroll
    for (int j = 0; j < 4; ++j)
      acc[i][j] = (floatx4)(0.0f);

  for (int k0 = 0; k0 < Dd; k0 += 32) {
    // pure async DMA for BOTH tiles; LDS dest linear, source column pre-swizzled
    gld16(A + (size_t)(m0 + r0) * Dd + k0 + c0, As + (size_t)u0 * 8);
    gld16(A + (size_t)(m0 + r1) * Dd + k0 + c1, As + (size_t)u1 * 8);
    gld16(W + (size_t)(n0 + r0) * Dd + k0 + c0, Bs + (size_t)u0 * 8);
    gld16(W + (size_t)(n0 + r1) * Dd + k0 + c1, Bs + (size_t)u1 * 8);
    __syncthreads();   // drains vmcnt (async LDS DMA)

    bf16x8 af[4], bfv[4];
    #pragma unroll
    for (int i = 0; i < 4; ++i) af[i]  = *(const bf16x8*)(As + (wm + i * 16 + fr) * 32 + soff);
    #pragma unroll
    for (int j = 0; j < 4; ++j) bfv[j] = *(const bf16x8*)(Bs + (wn + j * 16 + fr) * 32 + soff);
    #pragma unroll
    for (int i = 0; i < 4; ++i)
      #pragma unroll
      for (int j = 0; j < 4; ++j)
        acc[i][j] = __builtin_amdgcn_mfma_f32_16x16x32_bf16(af[i], bfv[j], acc[i][j], 0, 0, 0);
    __syncthreads();
  }

  // epilogue: C/D layout col = lane&15, row = (lane>>4)*4 + reg
  #pragma unroll
  for (int i = 0; i < 4; ++i) {
    int rbase = m0 + wm + i * 16 + (lane >> 4) * 4;
    #pragma unroll
    for (int j = 0; j < 4; ++j) {
      int col = n0 + wn + j * 16 + (lane & 15);
      #pragma unroll
      for (int r = 0; r < 4; ++r) {
        float v = acc[i][j][r];
        size_t off = (size_t)(rbase + r) * Dd + col;
        if (ACT == 0)      ((float*)Cout)[off] = v;
        else if (ACT == 1) ((bf16*)Cout)[off]  = (bf16)(1.0f / (1.0f + __expf(-v)));
        else               ((bf16*)Cout)[off]  = (bf16)v;
      }
    }
  }
}

// ---------------- WKV chunked scan (k, v bf16) ----------------
__global__ __launch_bounds__(256) void scan_partial(
    const bf16* __restrict__ k, const bf16* __restrict__ v,
    const float* __restrict__ td, float* __restrict__ Pa, float* __restrict__ Pb)
{
  int d = blockIdx.x * 256 + threadIdx.x;
  int b = blockIdx.y, c = blockIdx.z;
  float decay = __expf(-__expf(td[d]));
  size_t base = ((size_t)(b * Ll + c * CT)) * Dd + d;
  float pa = 0.0f, pb = 0.0f;
  #pragma unroll 4
  for (int t = 0; t < CT; ++t) {
    size_t idx = base + (size_t)t * Dd;
    float ek = __expf((float)k[idx]);
    pa = decay * pa + ek * (float)v[idx];
    pb = decay * pb + ek;
  }
  size_t o = ((size_t)(b * NC + c)) * Dd + d;
  Pa[o] = pa; Pb[o] = pb;
}

__global__ __launch_bounds__(256) void scan_combine(
    const float* __restrict__ td, const float* __restrict__ Pa, const float* __restrict__ Pb,
    float* __restrict__ A0, float* __restrict__ B0)
{
  int d = blockIdx.x * 256 + threadIdx.x;
  int b = blockIdx.y;
  float dT = __expf(-__expf(td[d]) * (float)CT);   // decay^CT
  float a = 0.0f, bb = 0.0f;
  for (int c = 0; c < NC; ++c) {
    size_t o = ((size_t)(b * NC + c)) * Dd + d;
    A0[o] = a; B0[o] = bb;
    a  = dT * a  + Pa[o];
    bb = dT * bb + Pb[o];
  }
}

// y written IN-PLACE over v (thread-local read-before-write at identical index)
__global__ __launch_bounds__(256) void scan_final(
    const bf16* __restrict__ k, bf16* __restrict__ vy, const bf16* __restrict__ r,
    const float* __restrict__ td, const float* __restrict__ tf,
    const float* __restrict__ A0, const float* __restrict__ B0)
{
  int d = blockIdx.x * 256 + threadIdx.x;
  int b = blockIdx.y, c = blockIdx.z;
  float decay = __expf(-__expf(td[d]));
  float u     = tf[d];
  size_t o = ((size_t)(b * NC + c)) * Dd + d;
  float a = A0[o], bb = B0[o];
  size_t base = ((size_t)(b * Ll + c * CT)) * Dd + d;
  for (int t = 0; t < CT; ++t) {
    size_t idx = base + (size_t)t * Dd;
    float kk = (float)k[idx];
    float vv = (float)vy[idx];
    float eku = __expf(u + kk);
    float wkv = (a + eku * vv) / fmaxf(bb + eku, 1e-6f);
    vy[idx] = (bf16)((float)r[idx] * wkv);
    float ek = __expf(kk);
    a  = decay * a  + ek * vv;
    bb = decay * bb + ek;
  }
}

// ---------------- launch ----------------
extern "C" void kernel_launch(void* const* d_in, const int* in_sizes, int n_in,
                              void* d_out, int out_size, void* d_ws, size_t ws_size,
                              hipStream_t stream)
{
  const float* x  = (const float*)d_in[0];
  const float* td = (const float*)d_in[1];
  const float* tf = (const float*)d_in[2];
  const float* mk = (const float*)d_in[3];
  const float* mv = (const float*)d_in[4];
  const float* mr = (const float*)d_in[5];
  const float* Wk = (const float*)d_in[6];
  const float* Wv = (const float*)d_in[7];
  const float* Wr = (const float*)d_in[8];
  const float* Wo = (const float*)d_in[9];
  float* out = (float*)d_out;           // output f32 (reference dtype)

  // ws: 3 bf16 [M,D] buffers (phased) + 4 partial arrays = exactly 100 MiB
  char* ws = (char*)d_ws;
  const size_t S2 = (size_t)M * Dd * sizeof(bf16);   // 33,554,432 B
  const size_t SP = (size_t)Bb * NC * Dd;            // 262,144 elems
  bf16* buf1 = (bf16*)(ws);              // xmk -> v -> y
  bf16* buf2 = (bf16*)(ws + S2);         // xmv -> xmr
  bf16* buf3 = (bf16*)(ws + 2 * S2);     // k (bf16)
  float* Pa = (float*)(ws + 3 * S2);
  float* Pb = Pa + SP;
  float* A0 = Pb + SP;
  float* B0 = A0 + SP;

  // scratch parked in d_out (dead before the final f32 write):
  //   lower 32 MiB: sigmoid(r) bf16          (as before)
  //   upper 32 MiB: Wk/Wv/Wr bf16 (2 MiB ea) (dead after gemm r)
  char* ob  = (char*)d_out;
  bf16* rr  = (bf16*)d_out;
  bf16* Wkb = (bf16*)(ob + ((size_t)32 << 20));
  bf16* Wvb = (bf16*)(ob + ((size_t)34 << 20));
  bf16* Wrb = (bf16*)(ob + ((size_t)36 << 20));
  // Wo bf16 (2 MiB) overlays Pa+Pb, which die after scan_combine
  bf16* Wob = (bf16*)Pa;

  dim3 gp((unsigned)((size_t)M * Dd / (256 * 8)));   // 8192 blocks
  dim3 gw((unsigned)((size_t)Dd * Dd / (256 * 8)));  // 512 blocks
  dim3 gg(Dd / 128, M / 128);                        // (8, 128)

  convw<<<gw, 256, 0, stream>>>(Wk, Wkb);
  convw<<<gw, 256, 0, stream>>>(Wv, Wvb);
  convw<<<gw, 256, 0, stream>>>(Wr, Wrb);

  prep2<<<gp, 256, 0, stream>>>(x, mk, mv, buf1, buf2);          // xmk, xmv
  gemm_bb<2><<<gg, 256, 0, stream>>>(buf1, Wkb, buf3);           // k  (bf16)  buf1 dead
  gemm_bb<2><<<gg, 256, 0, stream>>>(buf2, Wvb, buf1);           // v  (bf16)  buf2 dead
  prep1<<<gp, 256, 0, stream>>>(x, mr, buf2);                    // xmr
  gemm_bb<1><<<gg, 256, 0, stream>>>(buf2, Wrb, rr);             // sigmoid(r) -> d_out lo

  scan_partial<<<dim3(Dd / 256, Bb, NC), 256, 0, stream>>>(buf3, buf1, td, Pa, Pb);
  scan_combine<<<dim3(Dd / 256, Bb), 256, 0, stream>>>(td, Pa, Pb, A0, B0);
  convw<<<gw, 256, 0, stream>>>(Wo, Wob);                        // Pa/Pb now dead
  scan_final  <<<dim3(Dd / 256, Bb, NC), 256, 0, stream>>>(buf3, buf1, rr, td, tf, A0, B0);

  gemm_bb<0><<<gg, 256, 0, stream>>>(buf1, Wob, out);            // y·Wo -> d_out (f32)
}

// Round 2
// 350.028 us; speedup vs baseline: 1.4491x; 1.1535x over previous
//
#include <hip/hip_runtime.h>
#include <cstdint>
#include <cstddef>

typedef __bf16 bf16;
typedef __bf16 bf16x8 __attribute__((ext_vector_type(8)));
typedef float floatx4 __attribute__((ext_vector_type(4)));
typedef float floatx8 __attribute__((ext_vector_type(8)));
typedef unsigned int u32;

constexpr int Bb = 4, Ll = 4096, Dd = 1024;
constexpr int M  = Bb * Ll;          // 16384 rows
constexpr int NC = 64, CT = 64;      // chunks per sequence, chunk length

// async 16B global->LDS (width=16 emits global_load_lds_dwordx4)
typedef const __attribute__((address_space(1))) u32 glb_u32;
typedef __attribute__((address_space(3))) u32 lds_u32;
__device__ __forceinline__ void gld16(const bf16* g, bf16* l) {
  __builtin_amdgcn_global_load_lds((glb_u32*)g, (lds_u32*)l, 16, 0, 0);
}
// raw barrier (no vmcnt drain) + compiler memory fence so LDS reads can't
// hoist above / sink below it
__device__ __forceinline__ void bar() {
  __builtin_amdgcn_s_barrier();
  asm volatile("" ::: "memory");
}

// ---------------- W f32 -> bf16 converts ----------------
__global__ __launch_bounds__(256) void convw(
    const float* __restrict__ W, bf16* __restrict__ Wb)
{
  size_t base = ((size_t)blockIdx.x * 256 + threadIdx.x) * 8;
  floatx8 w = *(const floatx8*)(W + base);
  bf16x8 o;
  #pragma unroll
  for (int j = 0; j < 8; ++j) o[j] = (bf16)w[j];
  *(bf16x8*)(Wb + base) = o;
}

__global__ __launch_bounds__(256) void convw3(
    const float* __restrict__ Wa, const float* __restrict__ Wbp, const float* __restrict__ Wc,
    bf16* __restrict__ oa, bf16* __restrict__ ob, bf16* __restrict__ oc)
{
  const float* s = blockIdx.y == 0 ? Wa : (blockIdx.y == 1 ? Wbp : Wc);
  bf16*        d = blockIdx.y == 0 ? oa : (blockIdx.y == 1 ? ob  : oc);
  size_t base = ((size_t)blockIdx.x * 256 + threadIdx.x) * 8;
  floatx8 w = *(const floatx8*)(s + base);
  bf16x8 o;
  #pragma unroll
  for (int j = 0; j < 8; ++j) o[j] = (bf16)w[j];
  *(bf16x8*)(d + base) = o;
}

// ---------------- prep: token-shift mix, f32 x -> bf16 mixed arrays ----------------
__global__ __launch_bounds__(256) void prep2(
    const float* __restrict__ x, const float* __restrict__ ma, const float* __restrict__ mb,
    bf16* __restrict__ oa, bf16* __restrict__ ob)
{
  size_t base = ((size_t)blockIdx.x * 256 + threadIdx.x) * 8;
  int d = (int)(base & (size_t)(Dd - 1));
  int l = (int)((base / Dd) & (size_t)(Ll - 1));
  floatx8 xc = *(const floatx8*)(x + base);
  floatx8 xp = l ? *(const floatx8*)(x + base - Dd) : (floatx8)(0.0f);
  floatx8 a = *(const floatx8*)(ma + d);
  floatx8 b = *(const floatx8*)(mb + d);
  bf16x8 ra, rb;
  #pragma unroll
  for (int j = 0; j < 8; ++j) {
    ra[j] = (bf16)(xc[j] * a[j] + xp[j] * (1.0f - a[j]));
    rb[j] = (bf16)(xc[j] * b[j] + xp[j] * (1.0f - b[j]));
  }
  *(bf16x8*)(oa + base) = ra;
  *(bf16x8*)(ob + base) = rb;
}

__global__ __launch_bounds__(256) void prep1(
    const float* __restrict__ x, const float* __restrict__ ma, bf16* __restrict__ oa)
{
  size_t base = ((size_t)blockIdx.x * 256 + threadIdx.x) * 8;
  int d = (int)(base & (size_t)(Dd - 1));
  int l = (int)((base / Dd) & (size_t)(Ll - 1));
  floatx8 xc = *(const floatx8*)(x + base);
  floatx8 xp = l ? *(const floatx8*)(x + base - Dd) : (floatx8)(0.0f);
  floatx8 a = *(const floatx8*)(ma + d);
  bf16x8 ra;
  #pragma unroll
  for (int j = 0; j < 8; ++j)
    ra[j] = (bf16)(xc[j] * a[j] + xp[j] * (1.0f - a[j]));
  *(bf16x8*)(oa + base) = ra;
}

// ---------------- GEMM: 256x256 tile, BK=64, 8 waves, deep-pipelined ----------------
// C[m,n] = sum_k A[m,k]*W[n,k]; A,W bf16.
// Schedule (4 phases per K-tile, counted vmcnt, raw barriers, T2 swizzle, T5 setprio):
//   tile t lives in buf[t&1]; during iter t we stage tile t+1 into buf[(t+1)&1],
//   one half-tile per phase in slot order {A-low, B-low, B-high, A-high}.
//   Waits: vmcnt(4) at phases A,B,D (none at C) -> every half staged >=2 phases
//   before its wait; 2 half-tiles always in flight; never drains to 0 in the loop.
//   phase A: read A-low+B-low  -> MFMA (m-low  x n-low )   [needs t.Al,t.Bl  <= wait D(t-1)]
//   phase B: read B-high       -> MFMA (m-low  x n-high)   [needs t.Bh       <= wait A(t)  ]
//   phase C: read A-high       -> MFMA (m-high x n-high)   [needs t.Ah       <= wait B(t)  ]
//   phase D: (regs only)       -> MFMA (m-high x n-low )
// LDS swizzle: row = 64 bf16 = 8 x 16B units; read unit' = unit ^ (row&7); dest of
// global_load_lds stays linear, global SOURCE column pre-swizzled (same involution).
template <int ACT>
__global__ __launch_bounds__(512, 2) void gemm8(
    const bf16* __restrict__ A, const bf16* __restrict__ W, void* __restrict__ Cout)
{
  __shared__ __align__(16) bf16 sm[65536];   // 128 KiB: [buf][ A 16384 | B 16384 ]
  const int tid  = threadIdx.x;
  const int lane = tid & 63;
  const int w    = tid >> 6;              // 0..7
  const int wm   = (w >> 2) * 128;        // warp m offset (2 warps along M)
  const int wn   = (w & 3) * 64;          // warp n offset (4 warps along N)
  const int fr   = lane & 15;
  const int cu   = lane >> 4;             // 0..3
  const int key  = fr & 7;
  const int sw0  = ((cu)     ^ key) * 8;  // swizzled elem offset, ksub=0
  const int sw1  = ((4 | cu) ^ key) * 8;  // ksub=1
  const int aro  = wm + fr;
  const int bro  = wn + fr;

  // XCD-bijective swizzle: 256 blocks, 8 XCDs, chunk 32 (nwg%8==0)
  const int flat = (int)(blockIdx.y * 4 + blockIdx.x);
  const int nid  = (flat & 7) * 32 + (flat >> 3);
  const int m0   = (nid >> 2) * 256, n0 = (nid & 3) * 256;

  // staging: thread covers 16B units tid and tid+512 of each 1024-unit half (16 KiB)
  const int w0_ = tid, w1_ = tid + 512;
  const int lr0 = w0_ >> 3, sc0 = ((w0_ & 7) ^ (lr0 & 7)) * 8;
  const int lr1 = w1_ >> 3, sc1 = ((w1_ & 7) ^ (lr1 & 7)) * 8;
  const size_t rA0 = (size_t)(m0 + lr0) * Dd + sc0;
  const size_t rA1 = (size_t)(m0 + lr1) * Dd + sc1;
  const size_t rB0 = (size_t)(n0 + lr0) * Dd + sc0;
  const size_t rB1 = (size_t)(n0 + lr1) * Dd + sc1;
  const size_t HSTEP = (size_t)128 * Dd;   // +128 rows (the "high" half)

  floatx4 acc[8][4];
  #pragma unroll
  for (int i = 0; i < 8; ++i)
    #pragma unroll
    for (int j = 0; j < 4; ++j)
      acc[i][j] = (floatx4)(0.0f);

  // prologue: stage tile 0 (slot order Al, Bl, Bh, Ah), guarantee Al+Bl
  {
    bf16* A0 = sm;
    bf16* B0 = sm + 16384;
    gld16(A + rA0,         A0 + (size_t)w0_ * 8);
    gld16(A + rA1,         A0 + (size_t)w1_ * 8);
    gld16(W + rB0,         B0 + (size_t)w0_ * 8);
    gld16(W + rB1,         B0 + (size_t)w1_ * 8);
    gld16(W + rB0 + HSTEP, B0 + 8192 + (size_t)w0_ * 8);
    gld16(W + rB1 + HSTEP, B0 + 8192 + (size_t)w1_ * 8);
    gld16(A + rA0 + HSTEP, A0 + 8192 + (size_t)w0_ * 8);
    gld16(A + rA1 + HSTEP, A0 + 8192 + (size_t)w1_ * 8);
    asm volatile("s_waitcnt vmcnt(4)" ::: "memory");
    bar();
  }

  bf16x8 a[8], bl[4], bh[4];
  #pragma unroll 2
  for (int t = 0; t < 16; ++t) {
    const int p = t & 1;
    bf16* Ap = sm + p * 32768;
    bf16* Bp = Ap + 16384;
    bf16* Aq = sm + (p ^ 1) * 32768;
    bf16* Bq = Aq + 16384;
    const size_t kn = (size_t)((t < 15 ? t + 1 : 15) * 64);

    // ---- phase A: read A-low + B-low; stage (t+1).A-low ----
    #pragma unroll
    for (int i = 0; i < 4; ++i) {
      a[i * 2 + 0] = *(const bf16x8*)(Ap + (aro + i * 16) * 64 + sw0);
      a[i * 2 + 1] = *(const bf16x8*)(Ap + (aro + i * 16) * 64 + sw1);
    }
    #pragma unroll
    for (int j = 0; j < 2; ++j) {
      bl[j * 2 + 0] = *(const bf16x8*)(Bp + (bro + j * 16) * 64 + sw0);
      bl[j * 2 + 1] = *(const bf16x8*)(Bp + (bro + j * 16) * 64 + sw1);
    }
    gld16(A + rA0 + kn, Aq + (size_t)w0_ * 8);
    gld16(A + rA1 + kn, Aq + (size_t)w1_ * 8);
    asm volatile("s_waitcnt vmcnt(4)" ::: "memory");
    bar();
    __builtin_amdgcn_s_setprio(1);
    #pragma unroll
    for (int ks = 0; ks < 2; ++ks)
      #pragma unroll
      for (int i = 0; i < 4; ++i)
        #pragma unroll
        for (int j = 0; j < 2; ++j)
          acc[i][j] = __builtin_amdgcn_mfma_f32_16x16x32_bf16(a[i * 2 + ks], bl[j * 2 + ks], acc[i][j], 0, 0, 0);
    __builtin_amdgcn_s_setprio(0);
    bar();

    // ---- phase B: read B-high; stage (t+1).B-low ----
    #pragma unroll
    for (int j = 0; j < 2; ++j) {
      bh[j * 2 + 0] = *(const bf16x8*)(Bp + (bro + (j + 2) * 16) * 64 + sw0);
      bh[j * 2 + 1] = *(const bf16x8*)(Bp + (bro + (j + 2) * 16) * 64 + sw1);
    }
    gld16(W + rB0 + kn, Bq + (size_t)w0_ * 8);
    gld16(W + rB1 + kn, Bq + (size_t)w1_ * 8);
    asm volatile("s_waitcnt vmcnt(4)" ::: "memory");
    bar();
    __builtin_amdgcn_s_setprio(1);
    #pragma unroll
    for (int ks = 0; ks < 2; ++ks)
      #pragma unroll
      for (int i = 0; i < 4; ++i)
        #pragma unroll
        for (int j = 0; j < 2; ++j)
          acc[i][j + 2] = __builtin_amdgcn_mfma_f32_16x16x32_bf16(a[i * 2 + ks], bh[j * 2 + ks], acc[i][j + 2], 0, 0, 0);
    __builtin_amdgcn_s_setprio(0);
    bar();

    // ---- phase C: read A-high; stage (t+1).B-high (no wait this phase) ----
    #pragma unroll
    for (int i = 0; i < 4; ++i) {
      a[i * 2 + 0] = *(const bf16x8*)(Ap + (aro + (i + 4) * 16) * 64 + sw0);
      a[i * 2 + 1] = *(const bf16x8*)(Ap + (aro + (i + 4) * 16) * 64 + sw1);
    }
    gld16(W + rB0 + kn + HSTEP, Bq + 8192 + (size_t)w0_ * 8);
    gld16(W + rB1 + kn + HSTEP, Bq + 8192 + (size_t)w1_ * 8);
    bar();
    __builtin_amdgcn_s_setprio(1);
    #pragma unroll
    for (int ks = 0; ks < 2; ++ks)
      #pragma unroll
      for (int i = 0; i < 4; ++i)
        #pragma unroll
        for (int j = 0; j < 2; ++j)
          acc[i + 4][j + 2] = __builtin_amdgcn_mfma_f32_16x16x32_bf16(a[i * 2 + ks], bh[j * 2 + ks], acc[i + 4][j + 2], 0, 0, 0);
    __builtin_amdgcn_s_setprio(0);
    bar();

    // ---- phase D: regs only; stage (t+1).A-high ----
    gld16(A + rA0 + kn + HSTEP, Aq + 8192 + (size_t)w0_ * 8);
    gld16(A + rA1 + kn + HSTEP, Aq + 8192 + (size_t)w1_ * 8);
    asm volatile("s_waitcnt vmcnt(4)" ::: "memory");
    bar();
    __builtin_amdgcn_s_setprio(1);
    #pragma unroll
    for (int ks = 0; ks < 2; ++ks)
      #pragma unroll
      for (int i = 0; i < 4; ++i)
        #pragma unroll
        for (int j = 0; j < 2; ++j)
          acc[i + 4][j] = __builtin_amdgcn_mfma_f32_16x16x32_bf16(a[i * 2 + ks], bl[j * 2 + ks], acc[i + 4][j], 0, 0, 0);
    __builtin_amdgcn_s_setprio(0);
    bar();
  }
  asm volatile("s_waitcnt vmcnt(0)" ::: "memory");

  // epilogue: C/D layout col = lane&15, row = (lane>>4)*4 + reg
  #pragma unroll
  for (int mi = 0; mi < 8; ++mi) {
    int rbase = m0 + wm + mi * 16 + (lane >> 4) * 4;
    #pragma unroll
    for (int j = 0; j < 4; ++j) {
      int col = n0 + wn + j * 16 + (lane & 15);
      #pragma unroll
      for (int r = 0; r < 4; ++r) {
        float v = acc[mi][j][r];
        size_t off = (size_t)(rbase + r) * Dd + col;
        if (ACT == 0)      ((float*)Cout)[off] = v;
        else if (ACT == 1) ((bf16*)Cout)[off]  = (bf16)(1.0f / (1.0f + __expf(-v)));
        else               ((bf16*)Cout)[off]  = (bf16)v;
      }
    }
  }
}

// ---------------- WKV chunked scan (k, v bf16) ----------------
__global__ __launch_bounds__(256) void scan_partial(
    const bf16* __restrict__ k, const bf16* __restrict__ v,
    const float* __restrict__ td, float* __restrict__ Pa, float* __restrict__ Pb)
{
  int d = blockIdx.x * 256 + threadIdx.x;
  int b = blockIdx.y, c = blockIdx.z;
  float decay = __expf(-__expf(td[d]));
  size_t base = ((size_t)(b * Ll + c * CT)) * Dd + d;
  float pa = 0.0f, pb = 0.0f;
  #pragma unroll 4
  for (int t = 0; t < CT; ++t) {
    size_t idx = base + (size_t)t * Dd;
    float ek = __expf((float)k[idx]);
    pa = decay * pa + ek * (float)v[idx];
    pb = decay * pb + ek;
  }
  size_t o = ((size_t)(b * NC + c)) * Dd + d;
  Pa[o] = pa; Pb[o] = pb;
}

__global__ __launch_bounds__(256) void scan_combine(
    const float* __restrict__ td, const float* __restrict__ Pa, const float* __restrict__ Pb,
    float* __restrict__ A0, float* __restrict__ B0)
{
  int d = blockIdx.x * 256 + threadIdx.x;
  int b = blockIdx.y;
  float dT = __expf(-__expf(td[d]) * (float)CT);   // decay^CT
  float a = 0.0f, bb = 0.0f;
  for (int c = 0; c < NC; ++c) {
    size_t o = ((size_t)(b * NC + c)) * Dd + d;
    A0[o] = a; B0[o] = bb;
    a  = dT * a  + Pa[o];
    bb = dT * bb + Pb[o];
  }
}

// y written IN-PLACE over v (thread-local read-before-write at identical index)
__global__ __launch_bounds__(256) void scan_final(
    const bf16* __restrict__ k, bf16* __restrict__ vy, const bf16* __restrict__ r,
    const float* __restrict__ td, const float* __restrict__ tf,
    const float* __restrict__ A0, const float* __restrict__ B0)
{
  int d = blockIdx.x * 256 + threadIdx.x;
  int b = blockIdx.y, c = blockIdx.z;
  float decay = __expf(-__expf(td[d]));
  float u     = tf[d];
  size_t o = ((size_t)(b * NC + c)) * Dd + d;
  float a = A0[o], bb = B0[o];
  size_t base = ((size_t)(b * Ll + c * CT)) * Dd + d;
  for (int t = 0; t < CT; ++t) {
    size_t idx = base + (size_t)t * Dd;
    float kk = (float)k[idx];
    float vv = (float)vy[idx];
    float eku = __expf(u + kk);
    float wkv = (a + eku * vv) / fmaxf(bb + eku, 1e-6f);
    vy[idx] = (bf16)((float)r[idx] * wkv);
    float ek = __expf(kk);
    a  = decay * a  + ek * vv;
    bb = decay * bb + ek;
  }
}

// ---------------- launch ----------------
extern "C" void kernel_launch(void* const* d_in, const int* in_sizes, int n_in,
                              void* d_out, int out_size, void* d_ws, size_t ws_size,
                              hipStream_t stream)
{
  const float* x  = (const float*)d_in[0];
  const float* td = (const float*)d_in[1];
  const float* tf = (const float*)d_in[2];
  const float* mk = (const float*)d_in[3];
  const float* mv = (const float*)d_in[4];
  const float* mr = (const float*)d_in[5];
  const float* Wk = (const float*)d_in[6];
  const float* Wv = (const float*)d_in[7];
  const float* Wr = (const float*)d_in[8];
  const float* Wo = (const float*)d_in[9];
  float* out = (float*)d_out;           // output f32 (reference dtype)

  // ws: 3 bf16 [M,D] buffers (phased) + 4 partial arrays = exactly 100 MiB
  char* ws = (char*)d_ws;
  const size_t S2 = (size_t)M * Dd * sizeof(bf16);   // 33,554,432 B
  const size_t SP = (size_t)Bb * NC * Dd;            // 262,144 elems
  bf16* buf1 = (bf16*)(ws);              // xmk -> v -> y
  bf16* buf2 = (bf16*)(ws + S2);         // xmv -> xmr
  bf16* buf3 = (bf16*)(ws + 2 * S2);     // k (bf16)
  float* Pa = (float*)(ws + 3 * S2);
  float* Pb = Pa + SP;
  float* A0 = Pb + SP;
  float* B0 = A0 + SP;

  // scratch parked in d_out (dead before the final f32 write):
  //   lower 32 MiB: sigmoid(r) bf16
  //   upper region: Wk/Wv/Wr bf16 (2 MiB each), dead after the r-gemm
  char* ob  = (char*)d_out;
  bf16* rr  = (bf16*)d_out;
  bf16* Wkb = (bf16*)(ob + ((size_t)32 << 20));
  bf16* Wvb = (bf16*)(ob + ((size_t)34 << 20));
  bf16* Wrb = (bf16*)(ob + ((size_t)36 << 20));
  // Wo bf16 (2 MiB) overlays Pa+Pb, which die after scan_combine
  bf16* Wob = (bf16*)Pa;

  dim3 gp((unsigned)((size_t)M * Dd / (256 * 8)));   // 8192 blocks
  dim3 gw((unsigned)((size_t)Dd * Dd / (256 * 8)));  // 512 blocks
  dim3 gg(Dd / 256, M / 256);                        // (4, 64) = 256 blocks

  convw3<<<dim3(gw.x, 3), 256, 0, stream>>>(Wk, Wv, Wr, Wkb, Wvb, Wrb);

  prep2<<<gp, 256, 0, stream>>>(x, mk, mv, buf1, buf2);          // xmk, xmv
  gemm8<2><<<gg, 512, 0, stream>>>(buf1, Wkb, buf3);             // k  (bf16)  buf1 dead
  gemm8<2><<<gg, 512, 0, stream>>>(buf2, Wvb, buf1);             // v  (bf16)  buf2 dead
  prep1<<<gp, 256, 0, stream>>>(x, mr, buf2);                    // xmr
  gemm8<1><<<gg, 512, 0, stream>>>(buf2, Wrb, rr);               // sigmoid(r) -> d_out lo

  scan_partial<<<dim3(Dd / 256, Bb, NC), 256, 0, stream>>>(buf3, buf1, td, Pa, Pb);
  scan_combine<<<dim3(Dd / 256, Bb), 256, 0, stream>>>(td, Pa, Pb, A0, B0);
  convw<<<gw, 256, 0, stream>>>(Wo, Wob);                        // Pa/Pb now dead
  scan_final  <<<dim3(Dd / 256, Bb, NC), 256, 0, stream>>>(buf3, buf1, rr, td, tf, A0, B0);

  gemm8<0><<<gg, 512, 0, stream>>>(buf1, Wob, out);              // y·Wo -> d_out (f32)
}

// Round 3
// 338.318 us; speedup vs baseline: 1.4993x; 1.0346x over previous
//
#include <hip/hip_runtime.h>
#include <cstdint>
#include <cstddef>

typedef __bf16 bf16;
typedef __bf16 bf16x8 __attribute__((ext_vector_type(8)));
typedef float floatx4 __attribute__((ext_vector_type(4)));
typedef float floatx8 __attribute__((ext_vector_type(8)));
typedef unsigned int u32;

constexpr int Bb = 4, Ll = 4096, Dd = 1024;
constexpr int M  = Bb * Ll;          // 16384 rows
constexpr int NC = 64, CT = 64;      // chunks per sequence, chunk length

// async 16B global->LDS (width=16 emits global_load_lds_dwordx4)
typedef const __attribute__((address_space(1))) u32 glb_u32;
typedef __attribute__((address_space(3))) u32 lds_u32;
__device__ __forceinline__ void gld16(const bf16* g, bf16* l) {
  __builtin_amdgcn_global_load_lds((glb_u32*)g, (lds_u32*)l, 16, 0, 0);
}
// raw barrier (no vmcnt drain) + compiler memory fence
__device__ __forceinline__ void bar() {
  __builtin_amdgcn_s_barrier();
  asm volatile("" ::: "memory");
}

// ---------------- W f32 -> bf16 converts ----------------
__global__ __launch_bounds__(256) void convw(
    const float* __restrict__ W, bf16* __restrict__ Wb)
{
  size_t base = ((size_t)blockIdx.x * 256 + threadIdx.x) * 8;
  floatx8 w = *(const floatx8*)(W + base);
  bf16x8 o;
  #pragma unroll
  for (int j = 0; j < 8; ++j) o[j] = (bf16)w[j];
  *(bf16x8*)(Wb + base) = o;
}

__global__ __launch_bounds__(256) void convw3(
    const float* __restrict__ Wa, const float* __restrict__ Wbp, const float* __restrict__ Wc,
    bf16* __restrict__ oa, bf16* __restrict__ ob, bf16* __restrict__ oc)
{
  const float* s = blockIdx.y == 0 ? Wa : (blockIdx.y == 1 ? Wbp : Wc);
  bf16*        d = blockIdx.y == 0 ? oa : (blockIdx.y == 1 ? ob  : oc);
  size_t base = ((size_t)blockIdx.x * 256 + threadIdx.x) * 8;
  floatx8 w = *(const floatx8*)(s + base);
  bf16x8 o;
  #pragma unroll
  for (int j = 0; j < 8; ++j) o[j] = (bf16)w[j];
  *(bf16x8*)(d + base) = o;
}

// ---------------- prep: token-shift mix for all three branches in ONE x pass ----
__global__ __launch_bounds__(256) void prep3(
    const float* __restrict__ x, const float* __restrict__ ma, const float* __restrict__ mb,
    const float* __restrict__ mc,
    bf16* __restrict__ oa, bf16* __restrict__ ob, bf16* __restrict__ oc)
{
  size_t base = ((size_t)blockIdx.x * 256 + threadIdx.x) * 8;
  int d = (int)(base & (size_t)(Dd - 1));
  int l = (int)((base / Dd) & (size_t)(Ll - 1));
  floatx8 xc = *(const floatx8*)(x + base);
  floatx8 xp = l ? *(const floatx8*)(x + base - Dd) : (floatx8)(0.0f);
  floatx8 a = *(const floatx8*)(ma + d);
  floatx8 b = *(const floatx8*)(mb + d);
  floatx8 c = *(const floatx8*)(mc + d);
  bf16x8 ra, rb, rc;
  #pragma unroll
  for (int j = 0; j < 8; ++j) {
    ra[j] = (bf16)(xc[j] * a[j] + xp[j] * (1.0f - a[j]));
    rb[j] = (bf16)(xc[j] * b[j] + xp[j] * (1.0f - b[j]));
    rc[j] = (bf16)(xc[j] * c[j] + xp[j] * (1.0f - c[j]));
  }
  *(bf16x8*)(oa + base) = ra;
  *(bf16x8*)(ob + base) = rb;
  *(bf16x8*)(oc + base) = rc;
}

// ---------------- GEMM: 256x256 tile, BK=64, 8 waves, deep-pipelined ----------------
// C[m,n] = sum_k A[m,k]*W[n,k]; A,W bf16.
// 4 phases per K-tile; stage 1 half-tile per phase (order Al, Bl, Bh, Ah);
// vmcnt(4) waits ONLY at phases B and D (m201 discipline — 2 waits/K-tile):
//   at D(t-1): outstanding {Al(t),Bl(t),Bh(t),Ah(t)}=8 -> retires Al,Bl (phase A needs)
//   at B(t):   outstanding {Bh(t),Ah(t),Al(t+1),Bl(t+1)}=8 -> retires Bh AND Ah
//              (covers phases B and C; phase C needs no wait)
// lgkmcnt(8) throttle before the barrier in the 12-read phase (A) keeps the LDS
// queue shallow so staged DMA-writes aren't delayed behind it.
// LDS swizzle: row = 64 bf16 = 8 x 16B units; read unit' = unit ^ (row&7); dest of
// global_load_lds stays linear, global SOURCE column pre-swizzled (same involution).
template <int ACT>
__global__ __launch_bounds__(512, 2) void gemm8(
    const bf16* __restrict__ A, const bf16* __restrict__ W, void* __restrict__ Cout)
{
  __shared__ __align__(16) bf16 sm[65536];   // 128 KiB: [buf][ A 16384 | B 16384 ]
  const int tid  = threadIdx.x;
  const int lane = tid & 63;
  const int w    = tid >> 6;              // 0..7
  const int wm   = (w >> 2) * 128;        // warp m offset (2 warps along M)
  const int wn   = (w & 3) * 64;          // warp n offset (4 warps along N)
  const int fr   = lane & 15;
  const int cu   = lane >> 4;             // 0..3
  const int key  = fr & 7;
  const int sw0  = ((cu)     ^ key) * 8;  // swizzled elem offset, ksub=0
  const int sw1  = ((4 | cu) ^ key) * 8;  // ksub=1
  const int aro  = wm + fr;
  const int bro  = wn + fr;

  // XCD-bijective swizzle: 256 blocks, 8 XCDs, chunk 32 (nwg%8==0)
  const int flat = (int)(blockIdx.y * 4 + blockIdx.x);
  const int nid  = (flat & 7) * 32 + (flat >> 3);
  const int m0   = (nid >> 2) * 256, n0 = (nid & 3) * 256;

  // staging: thread covers 16B units tid and tid+512 of each 1024-unit half (16 KiB)
  const int w0_ = tid, w1_ = tid + 512;
  const int lr0 = w0_ >> 3, sc0 = ((w0_ & 7) ^ (lr0 & 7)) * 8;
  const int lr1 = w1_ >> 3, sc1 = ((w1_ & 7) ^ (lr1 & 7)) * 8;
  const size_t rA0 = (size_t)(m0 + lr0) * Dd + sc0;
  const size_t rA1 = (size_t)(m0 + lr1) * Dd + sc1;
  const size_t rB0 = (size_t)(n0 + lr0) * Dd + sc0;
  const size_t rB1 = (size_t)(n0 + lr1) * Dd + sc1;
  const size_t HSTEP = (size_t)128 * Dd;   // +128 rows (the "high" half)

  floatx4 acc[8][4];
  #pragma unroll
  for (int i = 0; i < 8; ++i)
    #pragma unroll
    for (int j = 0; j < 4; ++j)
      acc[i][j] = (floatx4)(0.0f);

  // prologue: stage tile 0 (slot order Al, Bl, Bh, Ah); vmcnt(4) retires Al,Bl
  {
    bf16* A0 = sm;
    bf16* B0 = sm + 16384;
    gld16(A + rA0,         A0 + (size_t)w0_ * 8);
    gld16(A + rA1,         A0 + (size_t)w1_ * 8);
    gld16(W + rB0,         B0 + (size_t)w0_ * 8);
    gld16(W + rB1,         B0 + (size_t)w1_ * 8);
    gld16(W + rB0 + HSTEP, B0 + 8192 + (size_t)w0_ * 8);
    gld16(W + rB1 + HSTEP, B0 + 8192 + (size_t)w1_ * 8);
    gld16(A + rA0 + HSTEP, A0 + 8192 + (size_t)w0_ * 8);
    gld16(A + rA1 + HSTEP, A0 + 8192 + (size_t)w1_ * 8);
    asm volatile("s_waitcnt vmcnt(4)" ::: "memory");
    bar();
  }

  bf16x8 a[8], bl[4], bh[4];
  #pragma unroll 2
  for (int t = 0; t < 16; ++t) {
    const int p = t & 1;
    bf16* Ap = sm + p * 32768;
    bf16* Bp = Ap + 16384;
    bf16* Aq = sm + (p ^ 1) * 32768;
    bf16* Bq = Aq + 16384;
    const size_t kn = (size_t)((t < 15 ? t + 1 : 15) * 64);

    // ---- phase A: read A-low + B-low; stage (t+1).A-low; NO vmcnt wait ----
    #pragma unroll
    for (int i = 0; i < 4; ++i) {
      a[i * 2 + 0] = *(const bf16x8*)(Ap + (aro + i * 16) * 64 + sw0);
      a[i * 2 + 1] = *(const bf16x8*)(Ap + (aro + i * 16) * 64 + sw1);
    }
    #pragma unroll
    for (int j = 0; j < 2; ++j) {
      bl[j * 2 + 0] = *(const bf16x8*)(Bp + (bro + j * 16) * 64 + sw0);
      bl[j * 2 + 1] = *(const bf16x8*)(Bp + (bro + j * 16) * 64 + sw1);
    }
    gld16(A + rA0 + kn, Aq + (size_t)w0_ * 8);
    gld16(A + rA1 + kn, Aq + (size_t)w1_ * 8);
    asm volatile("s_waitcnt lgkmcnt(8)" ::: "memory");   // throttle 12-read queue
    bar();
    __builtin_amdgcn_s_setprio(1);
    #pragma unroll
    for (int ks = 0; ks < 2; ++ks)
      #pragma unroll
      for (int i = 0; i < 4; ++i)
        #pragma unroll
        for (int j = 0; j < 2; ++j)
          acc[i][j] = __builtin_amdgcn_mfma_f32_16x16x32_bf16(a[i * 2 + ks], bl[j * 2 + ks], acc[i][j], 0, 0, 0);
    __builtin_amdgcn_s_setprio(0);
    bar();

    // ---- phase B: read B-high; stage (t+1).B-low; vmcnt(4) retires Bh(t)+Ah(t) ----
    #pragma unroll
    for (int j = 0; j < 2; ++j) {
      bh[j * 2 + 0] = *(const bf16x8*)(Bp + (bro + (j + 2) * 16) * 64 + sw0);
      bh[j * 2 + 1] = *(const bf16x8*)(Bp + (bro + (j + 2) * 16) * 64 + sw1);
    }
    gld16(W + rB0 + kn, Bq + (size_t)w0_ * 8);
    gld16(W + rB1 + kn, Bq + (size_t)w1_ * 8);
    asm volatile("s_waitcnt vmcnt(4)" ::: "memory");
    bar();
    __builtin_amdgcn_s_setprio(1);
    #pragma unroll
    for (int ks = 0; ks < 2; ++ks)
      #pragma unroll
      for (int i = 0; i < 4; ++i)
        #pragma unroll
        for (int j = 0; j < 2; ++j)
          acc[i][j + 2] = __builtin_amdgcn_mfma_f32_16x16x32_bf16(a[i * 2 + ks], bh[j * 2 + ks], acc[i][j + 2], 0, 0, 0);
    __builtin_amdgcn_s_setprio(0);
    bar();

    // ---- phase C: read A-high; stage (t+1).B-high; NO wait (covered by B's) ----
    #pragma unroll
    for (int i = 0; i < 4; ++i) {
      a[i * 2 + 0] = *(const bf16x8*)(Ap + (aro + (i + 4) * 16) * 64 + sw0);
      a[i * 2 + 1] = *(const bf16x8*)(Ap + (aro + (i + 4) * 16) * 64 + sw1);
    }
    gld16(W + rB0 + kn + HSTEP, Bq + 8192 + (size_t)w0_ * 8);
    gld16(W + rB1 + kn + HSTEP, Bq + 8192 + (size_t)w1_ * 8);
    bar();
    __builtin_amdgcn_s_setprio(1);
    #pragma unroll
    for (int ks = 0; ks < 2; ++ks)
      #pragma unroll
      for (int i = 0; i < 4; ++i)
        #pragma unroll
        for (int j = 0; j < 2; ++j)
          acc[i + 4][j + 2] = __builtin_amdgcn_mfma_f32_16x16x32_bf16(a[i * 2 + ks], bh[j * 2 + ks], acc[i + 4][j + 2], 0, 0, 0);
    __builtin_amdgcn_s_setprio(0);
    bar();

    // ---- phase D: regs only; stage (t+1).A-high; vmcnt(4) retires Al,Bl(t+1) ----
    gld16(A + rA0 + kn + HSTEP, Aq + 8192 + (size_t)w0_ * 8);
    gld16(A + rA1 + kn + HSTEP, Aq + 8192 + (size_t)w1_ * 8);
    asm volatile("s_waitcnt vmcnt(4)" ::: "memory");
    bar();
    __builtin_amdgcn_s_setprio(1);
    #pragma unroll
    for (int ks = 0; ks < 2; ++ks)
      #pragma unroll
      for (int i = 0; i < 4; ++i)
        #pragma unroll
        for (int j = 0; j < 2; ++j)
          acc[i + 4][j] = __builtin_amdgcn_mfma_f32_16x16x32_bf16(a[i * 2 + ks], bl[j * 2 + ks], acc[i + 4][j], 0, 0, 0);
    __builtin_amdgcn_s_setprio(0);
    bar();
  }
  asm volatile("s_waitcnt vmcnt(0)" ::: "memory");

  // epilogue: C/D layout col = lane&15, row = (lane>>4)*4 + reg
  #pragma unroll
  for (int mi = 0; mi < 8; ++mi) {
    int rbase = m0 + wm + mi * 16 + (lane >> 4) * 4;
    #pragma unroll
    for (int j = 0; j < 4; ++j) {
      int col = n0 + wn + j * 16 + (lane & 15);
      #pragma unroll
      for (int r = 0; r < 4; ++r) {
        float v = acc[mi][j][r];
        size_t off = (size_t)(rbase + r) * Dd + col;
        if (ACT == 0)      ((float*)Cout)[off] = v;
        else if (ACT == 1) ((bf16*)Cout)[off]  = (bf16)(1.0f / (1.0f + __expf(-v)));
        else               ((bf16*)Cout)[off]  = (bf16)v;
      }
    }
  }
}

// ---------------- WKV chunked scan (k, v bf16) ----------------
__global__ __launch_bounds__(256) void scan_partial(
    const bf16* __restrict__ k, const bf16* __restrict__ v,
    const float* __restrict__ td, float* __restrict__ Pa, float* __restrict__ Pb)
{
  int d = blockIdx.x * 256 + threadIdx.x;
  int b = blockIdx.y, c = blockIdx.z;
  float decay = __expf(-__expf(td[d]));
  size_t base = ((size_t)(b * Ll + c * CT)) * Dd + d;
  float pa = 0.0f, pb = 0.0f;
  #pragma unroll 4
  for (int t = 0; t < CT; ++t) {
    size_t idx = base + (size_t)t * Dd;
    float ek = __expf((float)k[idx]);
    pa = decay * pa + ek * (float)v[idx];
    pb = decay * pb + ek;
  }
  size_t o = ((size_t)(b * NC + c)) * Dd + d;
  Pa[o] = pa; Pb[o] = pb;
}

__global__ __launch_bounds__(256) void scan_combine(
    const float* __restrict__ td, const float* __restrict__ Pa, const float* __restrict__ Pb,
    float* __restrict__ A0, float* __restrict__ B0)
{
  int d = blockIdx.x * 256 + threadIdx.x;
  int b = blockIdx.y;
  float dT = __expf(-__expf(td[d]) * (float)CT);   // decay^CT
  float a = 0.0f, bb = 0.0f;
  for (int c = 0; c < NC; ++c) {
    size_t o = ((size_t)(b * NC + c)) * Dd + d;
    A0[o] = a; B0[o] = bb;
    a  = dT * a  + Pa[o];
    bb = dT * bb + Pb[o];
  }
}

// y written IN-PLACE over v (thread-local read-before-write at identical index)
__global__ __launch_bounds__(256) void scan_final(
    const bf16* __restrict__ k, bf16* __restrict__ vy, const bf16* __restrict__ r,
    const float* __restrict__ td, const float* __restrict__ tf,
    const float* __restrict__ A0, const float* __restrict__ B0)
{
  int d = blockIdx.x * 256 + threadIdx.x;
  int b = blockIdx.y, c = blockIdx.z;
  float decay = __expf(-__expf(td[d]));
  float u     = tf[d];
  size_t o = ((size_t)(b * NC + c)) * Dd + d;
  float a = A0[o], bb = B0[o];
  size_t base = ((size_t)(b * Ll + c * CT)) * Dd + d;
  for (int t = 0; t < CT; ++t) {
    size_t idx = base + (size_t)t * Dd;
    float kk = (float)k[idx];
    float vv = (float)vy[idx];
    float eku = __expf(u + kk);
    float wkv = (a + eku * vv) / fmaxf(bb + eku, 1e-6f);
    vy[idx] = (bf16)((float)r[idx] * wkv);
    float ek = __expf(kk);
    a  = decay * a  + ek * vv;
    bb = decay * bb + ek;
  }
}

// ---------------- launch ----------------
extern "C" void kernel_launch(void* const* d_in, const int* in_sizes, int n_in,
                              void* d_out, int out_size, void* d_ws, size_t ws_size,
                              hipStream_t stream)
{
  const float* x  = (const float*)d_in[0];
  const float* td = (const float*)d_in[1];
  const float* tf = (const float*)d_in[2];
  const float* mk = (const float*)d_in[3];
  const float* mv = (const float*)d_in[4];
  const float* mr = (const float*)d_in[5];
  const float* Wk = (const float*)d_in[6];
  const float* Wv = (const float*)d_in[7];
  const float* Wr = (const float*)d_in[8];
  const float* Wo = (const float*)d_in[9];
  float* out = (float*)d_out;           // output f32 (reference dtype)

  // ws: 3 bf16 [M,D] buffers (phased) + 4 partial arrays = exactly 100 MiB
  char* ws = (char*)d_ws;
  const size_t S2 = (size_t)M * Dd * sizeof(bf16);   // 33,554,432 B
  const size_t SP = (size_t)Bb * NC * Dd;            // 262,144 elems
  bf16* buf1 = (bf16*)(ws);              // xmk -> v -> y
  bf16* buf2 = (bf16*)(ws + S2);         // xmv
  bf16* buf3 = (bf16*)(ws + 2 * S2);     // xmr -> k (bf16)
  float* Pa = (float*)(ws + 3 * S2);
  float* Pb = Pa + SP;
  float* A0 = Pb + SP;
  float* B0 = A0 + SP;

  // scratch parked in d_out (dead before the final f32 write):
  //   lower 32 MiB: sigmoid(r) bf16
  //   upper region: Wk/Wv/Wr bf16 (2 MiB each), dead after their gemms
  char* ob  = (char*)d_out;
  bf16* rr  = (bf16*)d_out;
  bf16* Wkb = (bf16*)(ob + ((size_t)32 << 20));
  bf16* Wvb = (bf16*)(ob + ((size_t)34 << 20));
  bf16* Wrb = (bf16*)(ob + ((size_t)36 << 20));
  // Wo bf16 (2 MiB) overlays Pa+Pb, which die after scan_combine
  bf16* Wob = (bf16*)Pa;

  dim3 gp((unsigned)((size_t)M * Dd / (256 * 8)));   // 8192 blocks
  dim3 gw((unsigned)((size_t)Dd * Dd / (256 * 8)));  // 512 blocks
  dim3 gg(Dd / 256, M / 256);                        // (4, 64) = 256 blocks

  convw3<<<dim3(gw.x, 3), 256, 0, stream>>>(Wk, Wv, Wr, Wkb, Wvb, Wrb);

  // ONE x pass for all three token-shift mixes
  prep3<<<gp, 256, 0, stream>>>(x, mk, mv, mr, buf1, buf2, buf3);  // xmk, xmv, xmr

  gemm8<1><<<gg, 512, 0, stream>>>(buf3, Wrb, rr);               // sigmoid(r) -> d_out lo; buf3 dead
  gemm8<2><<<gg, 512, 0, stream>>>(buf1, Wkb, buf3);             // k  (bf16)  buf1 dead
  gemm8<2><<<gg, 512, 0, stream>>>(buf2, Wvb, buf1);             // v  (bf16)  buf2 dead

  scan_partial<<<dim3(Dd / 256, Bb, NC), 256, 0, stream>>>(buf3, buf1, td, Pa, Pb);
  scan_combine<<<dim3(Dd / 256, Bb), 256, 0, stream>>>(td, Pa, Pb, A0, B0);
  convw<<<gw, 256, 0, stream>>>(Wo, Wob);                        // Pa/Pb now dead
  scan_final  <<<dim3(Dd / 256, Bb, NC), 256, 0, stream>>>(buf3, buf1, rr, td, tf, A0, B0);

  gemm8<0><<<gg, 512, 0, stream>>>(buf1, Wob, out);              // y·Wo -> d_out (f32)
}